// Round 5
// baseline (871.082 us; speedup 1.0000x reference)
//
#include <hip/hip_runtime.h>
#include <hip/hip_fp16.h>
#include <math.h>

#define HH 128
#define WW 128
#define NPIX 16384
#define CIN 3
#define DD 32
#define QQ 128
#define MM 16
#define NBATCH 2
#define EPSF 1e-8f

// ---------------- conv1: 3x3, 3->32, relu, zero-pad SAME ----------------
__global__ __launch_bounds__(256) void conv1_kernel(
    const float* __restrict__ x, const float* __restrict__ w1,
    const float* __restrict__ b1, float* __restrict__ out)
{
    __shared__ float wlds[9 * CIN * DD];
    int t = threadIdx.x;
    for (int idx = t; idx < 9 * CIN * DD / 4; idx += 256)
        ((float4*)wlds)[idx] = ((const float4*)w1)[idx];
    __syncthreads();

    int ocq = t & 3;
    int pl  = t >> 2;
    int blk = blockIdx.x;                   // 512
    int b   = blk >> 8;
    int pix = (blk & 255) * 64 + pl;
    int i = pix >> 7, j = pix & 127;
    int ocb = ocq << 3;

    float4 acc0 = *(const float4*)(b1 + ocb);
    float4 acc1 = *(const float4*)(b1 + ocb + 4);
    #pragma unroll
    for (int dy = 0; dy < 3; dy++) {
        int ii = i + dy - 1;
        if (ii < 0 || ii >= HH) continue;
        #pragma unroll
        for (int dx = 0; dx < 3; dx++) {
            int jj = j + dx - 1;
            if (jj < 0 || jj >= WW) continue;
            const float* fr = x + ((size_t)((b << 14) + ii * WW + jj)) * CIN;
            float in0 = fr[0], in1 = fr[1], in2 = fr[2];
            const float* wp = wlds + (size_t)((dy * 3 + dx) * CIN) * DD + ocb;
            #pragma unroll
            for (int ic = 0; ic < 3; ic++) {
                float inv = (ic == 0) ? in0 : (ic == 1) ? in1 : in2;
                float4 w0 = *(const float4*)(wp + ic * DD);
                float4 w1v = *(const float4*)(wp + ic * DD + 4);
                acc0.x += inv * w0.x;  acc0.y += inv * w0.y;
                acc0.z += inv * w0.z;  acc0.w += inv * w0.w;
                acc1.x += inv * w1v.x; acc1.y += inv * w1v.y;
                acc1.z += inv * w1v.z; acc1.w += inv * w1v.w;
            }
        }
    }
    float* op = out + (((size_t)(b << 14) + pix) << 5) + ocb;
    float4 r0 = {fmaxf(acc0.x, 0.f), fmaxf(acc0.y, 0.f), fmaxf(acc0.z, 0.f), fmaxf(acc0.w, 0.f)};
    float4 r1 = {fmaxf(acc1.x, 0.f), fmaxf(acc1.y, 0.f), fmaxf(acc1.z, 0.f), fmaxf(acc1.w, 0.f)};
    *(float4*)op = r0;
    *(float4*)(op + 4) = r1;
}

// ---------------- conv2: 3x3, 32->32, relu ----------------
__global__ __launch_bounds__(256) void conv2_kernel(
    const float* __restrict__ fin, const float* __restrict__ w2,
    const float* __restrict__ b2, float* __restrict__ out)
{
    __shared__ float wlds[9 * DD * DD];    // 36.9 KB
    int t = threadIdx.x;
    for (int idx = t; idx < 9 * DD * DD / 4; idx += 256)
        ((float4*)wlds)[idx] = ((const float4*)w2)[idx];
    __syncthreads();

    int ocq = t & 3;
    int pl  = t >> 2;
    int blk = blockIdx.x;                   // 512
    int b   = blk >> 8;
    int pix = (blk & 255) * 64 + pl;
    int i = pix >> 7, j = pix & 127;
    int ocb = ocq << 3;

    float4 acc0 = *(const float4*)(b2 + ocb);
    float4 acc1 = *(const float4*)(b2 + ocb + 4);
    #pragma unroll
    for (int dy = 0; dy < 3; dy++) {
        int ii = i + dy - 1;
        if (ii < 0 || ii >= HH) continue;
        #pragma unroll
        for (int dx = 0; dx < 3; dx++) {
            int jj = j + dx - 1;
            if (jj < 0 || jj >= WW) continue;
            const float* fr = fin + (((size_t)(b << 14) + ii * WW + jj)) * DD;
            float iv[DD];
            #pragma unroll
            for (int c = 0; c < DD / 4; c++)
                ((float4*)iv)[c] = *(const float4*)(fr + c * 4);
            const float* wp = wlds + (size_t)((dy * 3 + dx) * DD) * DD + ocb;
            #pragma unroll
            for (int ic = 0; ic < DD; ic++) {
                float inv = iv[ic];
                float4 w0 = *(const float4*)(wp + ic * DD);
                float4 w1v = *(const float4*)(wp + ic * DD + 4);
                acc0.x += inv * w0.x;  acc0.y += inv * w0.y;
                acc0.z += inv * w0.z;  acc0.w += inv * w0.w;
                acc1.x += inv * w1v.x; acc1.y += inv * w1v.y;
                acc1.z += inv * w1v.z; acc1.w += inv * w1v.w;
            }
        }
    }
    float* op = out + (((size_t)(b << 14) + pix) << 5) + ocb;
    float4 r0 = {fmaxf(acc0.x, 0.f), fmaxf(acc0.y, 0.f), fmaxf(acc0.z, 0.f), fmaxf(acc0.w, 0.f)};
    float4 r1 = {fmaxf(acc1.x, 0.f), fmaxf(acc1.y, 0.f), fmaxf(acc1.z, 0.f), fmaxf(acc1.w, 0.f)};
    *(float4*)op = r0;
    *(float4*)(op + 4) = r1;
}

// ---------------- k/q 1x1 projections + row norms ----------------
__global__ __launch_bounds__(256) void kq_kernel(
    const float* __restrict__ fin, const float* __restrict__ wk,
    const float* __restrict__ bk, const float* __restrict__ wq,
    float* __restrict__ ksb, float* __restrict__ qsb,
    float* __restrict__ knorm, float* __restrict__ qnorm)
{
    int g  = blockIdx.x * 256 + threadIdx.x;  // B*N*32
    int oc = g & 31;
    int bp = g >> 5;
    const float* fr = fin + (size_t)bp * DD;
    float ak = bk[oc], aq = 0.0f;
    #pragma unroll
    for (int ic = 0; ic < DD; ic += 4) {
        float4 fv = *(const float4*)(fr + ic);
        ak += fv.x * wk[(ic + 0) * DD + oc];
        ak += fv.y * wk[(ic + 1) * DD + oc];
        ak += fv.z * wk[(ic + 2) * DD + oc];
        ak += fv.w * wk[(ic + 3) * DD + oc];
        aq += fv.x * wq[(ic + 0) * DD + oc];
        aq += fv.y * wq[(ic + 1) * DD + oc];
        aq += fv.z * wq[(ic + 2) * DD + oc];
        aq += fv.w * wq[(ic + 3) * DD + oc];
    }
    ksb[g] = ak;
    qsb[g] = aq;
    float ssk = ak * ak, ssq = aq * aq;
    #pragma unroll
    for (int m = 1; m < 32; m <<= 1) {
        ssk += __shfl_xor(ssk, m, 64);
        ssq += __shfl_xor(ssq, m, 64);
    }
    if (oc == 0) {
        knorm[bp] = sqrtf(ssk);
        qnorm[bp] = sqrtf(ssq);
    }
}

// ---------------- edge scores: exp(cosine), UNSCALED ---------------------
// The reference's softmax denominator is a per-batch GLOBAL scalar; since
// each iteration renormalizes h to unit length, that uniform scale cancels
// (EPS=1e-8 is ~7e-5 relative to the scaled norm -> negligible). So wT
// stores raw e^cos in [0.37, 2.72] and the sums/atomic machinery is gone.
__global__ __launch_bounds__(256) void edge_kernel(
    const float* __restrict__ ksb, const float* __restrict__ qsb,
    const float* __restrict__ knorm, const float* __restrict__ qnorm,
    float* __restrict__ wT)
{
    __shared__ float kt[144][36];   // +4 pad: breaks 32-stride bank aliasing
    __shared__ float qt[64][36];
    __shared__ float kn[144];
    __shared__ float qn[64];
    const int t   = threadIdx.x;
    const int blk = blockIdx.x;     // 512
    const int b   = blk >> 8;
    const int tl  = blk & 255;
    const int ti0 = (tl >> 4) << 3, tj0 = (tl & 15) << 3;
    const float* kb = ksb + ((size_t)b << 19);
    const float* qb = qsb + ((size_t)b << 19);

    for (int idx = t; idx < 144 * 8; idx += 256) {
        int row = idx >> 3, quad = idx & 7;
        int ar = row / 12, ac = row - ar * 12;
        int gi = min(max(ti0 + ar - 2, 0), HH - 1);
        int gj = min(max(tj0 + ac - 2, 0), WW - 1);
        *(float4*)&kt[row][quad << 2] =
            *(const float4*)(kb + ((size_t)(gi * WW + gj) << 5) + (quad << 2));
    }
    for (int idx = t; idx < 64 * 8; idx += 256) {
        int row = idx >> 3, quad = idx & 7;
        int gp = (ti0 + (row >> 3)) * WW + tj0 + (row & 7);
        *(float4*)&qt[row][quad << 2] =
            *(const float4*)(qb + ((size_t)gp << 5) + (quad << 2));
    }
    if (t < 144) {
        int ar = t / 12, ac = t - ar * 12;
        int gi = min(max(ti0 + ar - 2, 0), HH - 1);
        int gj = min(max(tj0 + ac - 2, 0), WW - 1);
        kn[t] = knorm[(b << 14) + gi * WW + gj];
    } else if (t < 208) {
        int r2 = t - 144;
        int gp = (ti0 + (r2 >> 3)) * WW + tj0 + (r2 & 7);
        qn[r2] = qnorm[(b << 14) + gp];
    }
    __syncthreads();

    const int nl = t >> 2, s = t & 3;
    const int p = nl >> 3, q = nl & 7;
    float4 qv[8];
    #pragma unroll
    for (int c = 0; c < 8; c++) qv[c] = *(const float4*)&qt[nl][c << 2];
    const float qnv = qn[nl];
    const int gp = (ti0 + p) * WW + tj0 + q;
    float* wrow = wT + (((size_t)(b << 14) + gp) << 5);
    for (int o = s; o < 25; o += 4) {
        int di = o / 5, dj = o - di * 5;      // 0..4
        int krow = (p + di) * 12 + (q + dj);  // halo coords
        const float* kr = &kt[krow][0];
        float dot = 0.0f;
        #pragma unroll
        for (int c = 0; c < 8; c++) {
            float4 kv = *(const float4*)(kr + (c << 2));
            dot += qv[c].x * kv.x + qv[c].y * kv.y + qv[c].z * kv.z + qv[c].w * kv.w;
        }
        float den = fmaxf(qnv * kn[krow], EPSF);
        wrow[o] = expf(dot / den);    // raw e^cos; global softmax scale cancels
    }
}

// ---------------- hinit fp32 -> fp16 ------------------------------------
__global__ __launch_bounds__(256) void h2half_kernel(
    const float* __restrict__ hin, __half* __restrict__ hout)
{
    int i = blockIdx.x * 256 + threadIdx.x;   // 524288 uint4 tasks
    const float4* s = (const float4*)hin + (size_t)i * 2;
    float4 a = s[0], c = s[1];
    __half2 p0 = __floats2half2_rn(a.x, a.y);
    __half2 p1 = __floats2half2_rn(a.z, a.w);
    __half2 p2 = __floats2half2_rn(c.x, c.y);
    __half2 p3 = __floats2half2_rn(c.z, c.w);
    uint4 o;
    o.x = *(unsigned int*)&p0;
    o.y = *(unsigned int*)&p1;
    o.z = *(unsigned int*)&p2;
    o.w = *(unsigned int*)&p3;
    ((uint4*)hout)[i] = o;
}

// ---------------- one propagation iteration: fp16 h, single pass ---------
// h stored fp16: the WHOLE 12x12 halo x 128 ch tile fits one LDS pass
// (36.9 KB as 144 x 16 uint4 of 8 halves) -> LDS ops/thread 280 -> 140,
// global stage loads 18 -> 9, h traffic per iter halves. Accumulate fp32,
// normalize fp32, store fp16. Unscaled weights (see edge_kernel). LDS
// 46.3 KB -> 3 blocks/CU. XCD slab mapping kept for L2 locality.
__global__ __launch_bounds__(256, 3) void prop_kernel(
    const __half* __restrict__ hin, __half* __restrict__ hout,
    const float* __restrict__ wT)
{
    __shared__ uint4 tile_s[144 * 17];     // 144 halo px x 16 slots, pad 17
    __shared__ float wts[64][28];          // 25 wts/px, 7xfloat4 rows
    const int t = threadIdx.x;
    const int x = blockIdx.x & 7;          // XCD slab
    const int r = blockIdx.x >> 3;         // 0..63 within slab
    const int g_tr = (x << 2) + (r >> 4);  // global tile-row 0..31
    const int b   = g_tr >> 4;
    const int ti0 = (g_tr & 15) << 3;
    const int tj0 = (r & 15) << 3;

    // wts staging: 64 px x 7 float4 (28 floats; 25 used), raw e^cos
    {
        const float4* wbase = (const float4*)wT;
        for (int idx = t; idx < 448; idx += 256) {
            int px = idx / 7, f = idx - px * 7;
            int gp0 = (ti0 + (px >> 3)) * WW + tj0 + (px & 7);
            *(float4*)&wts[px][f << 2] =
                wbase[(((size_t)(b << 14) + gp0) << 3) + f];
        }
    }

    const int s  = t & 15;                 // uint4 slot (8 ch)
    const int g  = t >> 4;                 // 0..15
    const int q  = g & 7;                  // col within tile
    const int rb = g >> 3;                 // row-half 0/1

    // hoisted halo addressing: 9 staging px / thread (12x12 halo)
    int stoff[9], tidx[9];
    #pragma unroll
    for (int n = 0; n < 9; n++) {
        int a = (n << 4) + g;              // halo px 0..143
        int ar = a / 12, ac = a - ar * 12;
        int gi = min(max(ti0 + ar - 2, 0), HH - 1);
        int gj = min(max(tj0 + ac - 2, 0), WW - 1);
        stoff[n] = ((gi * WW + gj) << 4) + s;
        tidx[n]  = a * 17 + s;
    }
    const uint4* hb = (const uint4*)hin + ((size_t)b << 18);
    #pragma unroll
    for (int n = 0; n < 9; n++)
        tile_s[tidx[n]] = hb[stoff[n]];
    __syncthreads();

    float acc[4][8];
    #pragma unroll
    for (int k = 0; k < 4; k++)
        #pragma unroll
        for (int c = 0; c < 8; c++) acc[k][c] = 0.0f;

    #pragma unroll
    for (int dj = 0; dj < 5; dj++) {
        int ccol = q + dj;
        #pragma unroll
        for (int a = 0; a < 8; a++) {
            uint4 v = tile_s[(((rb << 2) + a) * 12 + ccol) * 17 + s];
            __half2 u0 = *(__half2*)&v.x;
            __half2 u1 = *(__half2*)&v.y;
            __half2 u2 = *(__half2*)&v.z;
            __half2 u3 = *(__half2*)&v.w;
            float2 f0 = __half22float2(u0);
            float2 f1 = __half22float2(u1);
            float2 f2 = __half22float2(u2);
            float2 f3 = __half22float2(u3);
            #pragma unroll
            for (int k = 0; k < 4; k++) {
                if (k < a - 4 || k > a) continue;   // compile-time pruned
                float w = wts[(((rb << 2) + k) << 3) + q][(a - k) * 5 + dj];
                acc[k][0] += w * f0.x;  acc[k][1] += w * f0.y;
                acc[k][2] += w * f1.x;  acc[k][3] += w * f1.y;
                acc[k][4] += w * f2.x;  acc[k][5] += w * f2.y;
                acc[k][6] += w * f3.x;  acc[k][7] += w * f3.y;
            }
        }
    }

    uint4* ob = (uint4*)hout + ((size_t)b << 18);
    #pragma unroll
    for (int k = 0; k < 4; k++) {
        float ss = acc[k][0] * acc[k][0] + acc[k][1] * acc[k][1] +
                   acc[k][2] * acc[k][2] + acc[k][3] * acc[k][3] +
                   acc[k][4] * acc[k][4] + acc[k][5] * acc[k][5] +
                   acc[k][6] * acc[k][6] + acc[k][7] * acc[k][7];
        ss += __shfl_xor(ss, 1, 64);
        ss += __shfl_xor(ss, 2, 64);
        ss += __shfl_xor(ss, 4, 64);
        ss += __shfl_xor(ss, 8, 64);
        float rs = 1.0f / (sqrtf(ss) + EPSF);
        __half2 p0 = __floats2half2_rn(acc[k][0] * rs, acc[k][1] * rs);
        __half2 p1 = __floats2half2_rn(acc[k][2] * rs, acc[k][3] * rs);
        __half2 p2 = __floats2half2_rn(acc[k][4] * rs, acc[k][5] * rs);
        __half2 p3 = __floats2half2_rn(acc[k][6] * rs, acc[k][7] * rs);
        uint4 o;
        o.x = *(unsigned int*)&p0;
        o.y = *(unsigned int*)&p1;
        o.z = *(unsigned int*)&p2;
        o.w = *(unsigned int*)&p3;
        int gp = (ti0 + (rb << 2) + k) * WW + (tj0 + q);
        ob[((size_t)gp << 4) + s] = o;
    }
}

// ---------------- mask head: h(fp16) @ w_mask, softmax(16), transpose ----
__global__ __launch_bounds__(256) void mask_kernel(
    const __half* __restrict__ h, const float* __restrict__ wm,
    float* __restrict__ out)
{
    __shared__ float wls[QQ * MM];      // 8 KB, [c][m] native layout
    __shared__ float part[64][4][20];   // [px][slot][16m + pad]
    const int t = threadIdx.x;
    for (int idx = t; idx < QQ * MM / 4; idx += 256)
        ((float4*)wls)[idx] = ((const float4*)wm)[idx];
    const int blk = blockIdx.x;         // 512
    const int b   = blk >> 8;
    const int n0  = (blk & 255) << 6;
    const int px  = t >> 2, s = t & 3;
    const __half* hr = h + (((size_t)(b << 14) + n0 + px) << 7);

    float hv[32];
    #pragma unroll
    for (int k = 0; k < 32; k++) hv[k] = __half2float(hr[s + (k << 2)]);
    __syncthreads();

    float4 a0 = {0,0,0,0}, a1 = a0, a2 = a0, a3 = a0;
    #pragma unroll
    for (int k = 0; k < 32; k++) {
        const float4* wrow = (const float4*)(wls + ((s + (k << 2)) << 4));
        float v = hv[k];
        float4 w0 = wrow[0], w1 = wrow[1], w2 = wrow[2], w3 = wrow[3];
        a0.x += v * w0.x; a0.y += v * w0.y; a0.z += v * w0.z; a0.w += v * w0.w;
        a1.x += v * w1.x; a1.y += v * w1.y; a1.z += v * w1.z; a1.w += v * w1.w;
        a2.x += v * w2.x; a2.y += v * w2.y; a2.z += v * w2.z; a2.w += v * w2.w;
        a3.x += v * w3.x; a3.y += v * w3.y; a3.z += v * w3.z; a3.w += v * w3.w;
    }
    *(float4*)&part[px][s][0]  = a0;
    *(float4*)&part[px][s][4]  = a1;
    *(float4*)&part[px][s][8]  = a2;
    *(float4*)&part[px][s][12] = a3;
    __syncthreads();

    float4 rr = {0,0,0,0};
    #pragma unroll
    for (int ss = 0; ss < 4; ss++) {
        float4 v = *(const float4*)&part[px][ss][s << 2];
        rr.x += v.x; rr.y += v.y; rr.z += v.z; rr.w += v.w;
    }
    float mx = fmaxf(fmaxf(rr.x, rr.y), fmaxf(rr.z, rr.w));
    mx = fmaxf(mx, __shfl_xor(mx, 1, 64));
    mx = fmaxf(mx, __shfl_xor(mx, 2, 64));
    float4 e = {expf(rr.x - mx), expf(rr.y - mx), expf(rr.z - mx), expf(rr.w - mx)};
    float ls = e.x + e.y + e.z + e.w;
    ls += __shfl_xor(ls, 1, 64);
    ls += __shfl_xor(ls, 2, 64);
    float inv = 1.0f / ls;
    float* ob = out + (((size_t)((b << 4) + (s << 2))) << 14) + n0 + px;
    ob[0]             = e.x * inv;
    ob[1 << 14]       = e.y * inv;
    ob[2 << 14]       = e.z * inv;
    ob[3 * (1 << 14)] = e.w * inv;
}

extern "C" void kernel_launch(void* const* d_in, const int* in_sizes, int n_in,
                              void* d_out, int out_size, void* d_ws, size_t ws_size,
                              hipStream_t stream)
{
    const float* x     = (const float*)d_in[0];
    // d_in[1] = edges (int32) -- unused: row/col are analytic
    const float* w1    = (const float*)d_in[2];
    const float* b1    = (const float*)d_in[3];
    const float* w2    = (const float*)d_in[4];
    const float* b2    = (const float*)d_in[5];
    const float* wk    = (const float*)d_in[6];
    const float* bk    = (const float*)d_in[7];
    const float* wq    = (const float*)d_in[8];
    const float* hinit = (const float*)d_in[9];
    const float* wm    = (const float*)d_in[10];
    float* out = (float*)d_out;

    char* ws = (char*)d_ws;
    size_t off = 0;
    auto alloc = [&](size_t bytes) -> void* {
        void* p = ws + off;
        off += (bytes + 255) & ~(size_t)255;
        return p;
    };
    float* feat1 = (float*)alloc((size_t)NBATCH * NPIX * DD * 4);
    float* feat2 = (float*)alloc((size_t)NBATCH * NPIX * DD * 4);
    float* ksb   = (float*)alloc((size_t)NBATCH * NPIX * DD * 4);
    float* qsb   = (float*)alloc((size_t)NBATCH * NPIX * DD * 4);
    float* knorm = (float*)alloc((size_t)NBATCH * NPIX * 4);
    float* qnorm = (float*)alloc((size_t)NBATCH * NPIX * 4);
    float* wT    = (float*)alloc((size_t)NBATCH * NPIX * 32 * 4);
    __half* h16A = (__half*)alloc((size_t)NBATCH * NPIX * QQ * 2);
    __half* h16B = (__half*)alloc((size_t)NBATCH * NPIX * QQ * 2);

    conv1_kernel<<<512, 256, 0, stream>>>(x, w1, b1, feat1);
    conv2_kernel<<<512, 256, 0, stream>>>(feat1, w2, b2, feat2);
    kq_kernel<<<4096, 256, 0, stream>>>(feat2, wk, bk, wq, ksb, qsb, knorm, qnorm);
    edge_kernel<<<512, 256, 0, stream>>>(ksb, qsb, knorm, qnorm, wT);

    h2half_kernel<<<2048, 256, 0, stream>>>(hinit, h16A);

    const __half* src = h16A;
    __half* dst = h16B;
    for (int it = 0; it < 32; it++) {
        prop_kernel<<<512, 256, 0, stream>>>(src, dst, wT);
        src = dst;
        dst = (dst == h16A) ? h16B : h16A;
    }
    mask_kernel<<<512, 256, 0, stream>>>(src, wm, out);
}

// Round 6
// 509.107 us; speedup vs baseline: 1.7110x; 1.7110x over previous
//
#include <hip/hip_runtime.h>
#include <math.h>

#define HH 128
#define WW 128
#define NPIX 16384
#define CIN 3
#define DD 32
#define QQ 128
#define MM 16
#define NBATCH 2
#define EPSF 1e-8f

// ---------------- conv1: 3x3, 3->32, relu, zero-pad SAME ----------------
__global__ __launch_bounds__(256) void conv1_kernel(
    const float* __restrict__ x, const float* __restrict__ w1,
    const float* __restrict__ b1, float* __restrict__ out)
{
    __shared__ float wlds[9 * CIN * DD];
    int t = threadIdx.x;
    for (int idx = t; idx < 9 * CIN * DD / 4; idx += 256)
        ((float4*)wlds)[idx] = ((const float4*)w1)[idx];
    __syncthreads();

    int ocq = t & 3;
    int pl  = t >> 2;
    int blk = blockIdx.x;                   // 512
    int b   = blk >> 8;
    int pix = (blk & 255) * 64 + pl;
    int i = pix >> 7, j = pix & 127;
    int ocb = ocq << 3;

    float4 acc0 = *(const float4*)(b1 + ocb);
    float4 acc1 = *(const float4*)(b1 + ocb + 4);
    #pragma unroll
    for (int dy = 0; dy < 3; dy++) {
        int ii = i + dy - 1;
        if (ii < 0 || ii >= HH) continue;
        #pragma unroll
        for (int dx = 0; dx < 3; dx++) {
            int jj = j + dx - 1;
            if (jj < 0 || jj >= WW) continue;
            const float* fr = x + ((size_t)((b << 14) + ii * WW + jj)) * CIN;
            float in0 = fr[0], in1 = fr[1], in2 = fr[2];
            const float* wp = wlds + (size_t)((dy * 3 + dx) * CIN) * DD + ocb;
            #pragma unroll
            for (int ic = 0; ic < 3; ic++) {
                float inv = (ic == 0) ? in0 : (ic == 1) ? in1 : in2;
                float4 w0 = *(const float4*)(wp + ic * DD);
                float4 w1v = *(const float4*)(wp + ic * DD + 4);
                acc0.x += inv * w0.x;  acc0.y += inv * w0.y;
                acc0.z += inv * w0.z;  acc0.w += inv * w0.w;
                acc1.x += inv * w1v.x; acc1.y += inv * w1v.y;
                acc1.z += inv * w1v.z; acc1.w += inv * w1v.w;
            }
        }
    }
    float* op = out + (((size_t)(b << 14) + pix) << 5) + ocb;
    float4 r0 = {fmaxf(acc0.x, 0.f), fmaxf(acc0.y, 0.f), fmaxf(acc0.z, 0.f), fmaxf(acc0.w, 0.f)};
    float4 r1 = {fmaxf(acc1.x, 0.f), fmaxf(acc1.y, 0.f), fmaxf(acc1.z, 0.f), fmaxf(acc1.w, 0.f)};
    *(float4*)op = r0;
    *(float4*)(op + 4) = r1;
}

// ---------------- conv2: 3x3, 32->32, relu ----------------
__global__ __launch_bounds__(256) void conv2_kernel(
    const float* __restrict__ fin, const float* __restrict__ w2,
    const float* __restrict__ b2, float* __restrict__ out)
{
    __shared__ float wlds[9 * DD * DD];    // 36.9 KB
    int t = threadIdx.x;
    for (int idx = t; idx < 9 * DD * DD / 4; idx += 256)
        ((float4*)wlds)[idx] = ((const float4*)w2)[idx];
    __syncthreads();

    int ocq = t & 3;
    int pl  = t >> 2;
    int blk = blockIdx.x;                   // 512
    int b   = blk >> 8;
    int pix = (blk & 255) * 64 + pl;
    int i = pix >> 7, j = pix & 127;
    int ocb = ocq << 3;

    float4 acc0 = *(const float4*)(b2 + ocb);
    float4 acc1 = *(const float4*)(b2 + ocb + 4);
    #pragma unroll
    for (int dy = 0; dy < 3; dy++) {
        int ii = i + dy - 1;
        if (ii < 0 || ii >= HH) continue;
        #pragma unroll
        for (int dx = 0; dx < 3; dx++) {
            int jj = j + dx - 1;
            if (jj < 0 || jj >= WW) continue;
            const float* fr = fin + (((size_t)(b << 14) + ii * WW + jj)) * DD;
            float iv[DD];
            #pragma unroll
            for (int c = 0; c < DD / 4; c++)
                ((float4*)iv)[c] = *(const float4*)(fr + c * 4);
            const float* wp = wlds + (size_t)((dy * 3 + dx) * DD) * DD + ocb;
            #pragma unroll
            for (int ic = 0; ic < DD; ic++) {
                float inv = iv[ic];
                float4 w0 = *(const float4*)(wp + ic * DD);
                float4 w1v = *(const float4*)(wp + ic * DD + 4);
                acc0.x += inv * w0.x;  acc0.y += inv * w0.y;
                acc0.z += inv * w0.z;  acc0.w += inv * w0.w;
                acc1.x += inv * w1v.x; acc1.y += inv * w1v.y;
                acc1.z += inv * w1v.z; acc1.w += inv * w1v.w;
            }
        }
    }
    float* op = out + (((size_t)(b << 14) + pix) << 5) + ocb;
    float4 r0 = {fmaxf(acc0.x, 0.f), fmaxf(acc0.y, 0.f), fmaxf(acc0.z, 0.f), fmaxf(acc0.w, 0.f)};
    float4 r1 = {fmaxf(acc1.x, 0.f), fmaxf(acc1.y, 0.f), fmaxf(acc1.z, 0.f), fmaxf(acc1.w, 0.f)};
    *(float4*)op = r0;
    *(float4*)(op + 4) = r1;
}

// ---------------- k/q 1x1 projections + row norms ----------------
__global__ __launch_bounds__(256) void kq_kernel(
    const float* __restrict__ fin, const float* __restrict__ wk,
    const float* __restrict__ bk, const float* __restrict__ wq,
    float* __restrict__ ksb, float* __restrict__ qsb,
    float* __restrict__ knorm, float* __restrict__ qnorm)
{
    int g  = blockIdx.x * 256 + threadIdx.x;  // B*N*32
    int oc = g & 31;
    int bp = g >> 5;
    const float* fr = fin + (size_t)bp * DD;
    float ak = bk[oc], aq = 0.0f;
    #pragma unroll
    for (int ic = 0; ic < DD; ic += 4) {
        float4 fv = *(const float4*)(fr + ic);
        ak += fv.x * wk[(ic + 0) * DD + oc];
        ak += fv.y * wk[(ic + 1) * DD + oc];
        ak += fv.z * wk[(ic + 2) * DD + oc];
        ak += fv.w * wk[(ic + 3) * DD + oc];
        aq += fv.x * wq[(ic + 0) * DD + oc];
        aq += fv.y * wq[(ic + 1) * DD + oc];
        aq += fv.z * wq[(ic + 2) * DD + oc];
        aq += fv.w * wq[(ic + 3) * DD + oc];
    }
    ksb[g] = ak;
    qsb[g] = aq;
    float ssk = ak * ak, ssq = aq * aq;
    #pragma unroll
    for (int m = 1; m < 32; m <<= 1) {
        ssk += __shfl_xor(ssk, m, 64);
        ssq += __shfl_xor(ssq, m, 64);
    }
    if (oc == 0) {
        knorm[bp] = sqrtf(ssk);
        qnorm[bp] = sqrtf(ssq);
    }
}

// ---------------- edge scores: exp(cosine), UNSCALED ---------------------
// Global softmax denominator cancels under per-iteration normalization
// (proven R5: absmax bit-identical). wT stores raw e^cos in [0.37, 2.72].
__global__ __launch_bounds__(256) void edge_kernel(
    const float* __restrict__ ksb, const float* __restrict__ qsb,
    const float* __restrict__ knorm, const float* __restrict__ qnorm,
    float* __restrict__ wT)
{
    __shared__ float kt[144][36];   // +4 pad: breaks 32-stride bank aliasing
    __shared__ float qt[64][36];
    __shared__ float kn[144];
    __shared__ float qn[64];
    const int t   = threadIdx.x;
    const int blk = blockIdx.x;     // 512
    const int b   = blk >> 8;
    const int tl  = blk & 255;
    const int ti0 = (tl >> 4) << 3, tj0 = (tl & 15) << 3;
    const float* kb = ksb + ((size_t)b << 19);
    const float* qb = qsb + ((size_t)b << 19);

    for (int idx = t; idx < 144 * 8; idx += 256) {
        int row = idx >> 3, quad = idx & 7;
        int ar = row / 12, ac = row - ar * 12;
        int gi = min(max(ti0 + ar - 2, 0), HH - 1);
        int gj = min(max(tj0 + ac - 2, 0), WW - 1);
        *(float4*)&kt[row][quad << 2] =
            *(const float4*)(kb + ((size_t)(gi * WW + gj) << 5) + (quad << 2));
    }
    for (int idx = t; idx < 64 * 8; idx += 256) {
        int row = idx >> 3, quad = idx & 7;
        int gp = (ti0 + (row >> 3)) * WW + tj0 + (row & 7);
        *(float4*)&qt[row][quad << 2] =
            *(const float4*)(qb + ((size_t)gp << 5) + (quad << 2));
    }
    if (t < 144) {
        int ar = t / 12, ac = t - ar * 12;
        int gi = min(max(ti0 + ar - 2, 0), HH - 1);
        int gj = min(max(tj0 + ac - 2, 0), WW - 1);
        kn[t] = knorm[(b << 14) + gi * WW + gj];
    } else if (t < 208) {
        int r2 = t - 144;
        int gp = (ti0 + (r2 >> 3)) * WW + tj0 + (r2 & 7);
        qn[r2] = qnorm[(b << 14) + gp];
    }
    __syncthreads();

    const int nl = t >> 2, s = t & 3;
    const int p = nl >> 3, q = nl & 7;
    float4 qv[8];
    #pragma unroll
    for (int c = 0; c < 8; c++) qv[c] = *(const float4*)&qt[nl][c << 2];
    const float qnv = qn[nl];
    const int gp = (ti0 + p) * WW + tj0 + q;
    float* wrow = wT + (((size_t)(b << 14) + gp) << 5);
    for (int o = s; o < 25; o += 4) {
        int di = o / 5, dj = o - di * 5;      // 0..4
        int krow = (p + di) * 12 + (q + dj);  // halo coords
        const float* kr = &kt[krow][0];
        float dot = 0.0f;
        #pragma unroll
        for (int c = 0; c < 8; c++) {
            float4 kv = *(const float4*)(kr + (c << 2));
            dot += qv[c].x * kv.x + qv[c].y * kv.y + qv[c].z * kv.z + qv[c].w * kv.w;
        }
        float den = fmaxf(qnv * kn[krow], EPSF);
        wrow[o] = expf(dot / den);
    }
}

// ---------------- one propagation iteration (proven R0/R3 structure) -----
__global__ __launch_bounds__(256) void prop_kernel(
    const float* __restrict__ hin, float* __restrict__ hout,
    const float* __restrict__ wT)
{
    __shared__ float4 tile_s[144 * 17];    // 12x12 px x 16 slots, pad 17
    __shared__ float wts[64][36];          // raw e^cos weights
    const int t = threadIdx.x;
    const int x = blockIdx.x & 7;          // XCD slab
    const int r = blockIdx.x >> 3;         // 0..63 within slab
    const int g_tr = (x << 2) + (r >> 4);  // global tile-row 0..31
    const int b   = g_tr >> 4;
    const int ti0 = (g_tr & 15) << 3;
    const int tj0 = (r & 15) << 3;

    {
        const float* wbase = wT + (((size_t)(b << 14) + ti0 * WW + tj0) << 5);
        for (int idx = t; idx < 512; idx += 256) {
            int p = idx >> 6, rest = idx & 63;
            float4 v = *(const float4*)(wbase + (((size_t)p * WW) << 5) + (rest << 2));
            int nl = (p << 3) + (rest >> 3);
            int c4 = (rest & 7) << 2;
            *(float4*)&wts[nl][c4] = v;
        }
    }

    const int s  = t & 15;
    const int g  = t >> 4;
    const int q  = g & 7;
    const int rb = g >> 3;

    const float* hb = hin + ((size_t)b << 21);

    float4 acc[2][4];
    #pragma unroll
    for (int sl = 0; sl < 2; sl++)
        #pragma unroll
        for (int k = 0; k < 4; k++) acc[sl][k] = {0.f, 0.f, 0.f, 0.f};

    #pragma unroll
    for (int sl = 0; sl < 2; sl++) {
        if (sl) __syncthreads();           // WAR: slab0 reads done
        int c0 = sl << 6;
        #pragma unroll
        for (int a0 = 0; a0 < 144; a0 += 16) {
            int a = a0 + g;
            int ar = a / 12, ac = a - ar * 12;
            int gi = min(max(ti0 + ar - 2, 0), HH - 1);
            int gj = min(max(tj0 + ac - 2, 0), WW - 1);
            tile_s[a * 17 + s] =
                *(const float4*)(hb + ((size_t)(gi * WW + gj) << 7) + c0 + (s << 2));
        }
        __syncthreads();

        #pragma unroll
        for (int dj = 0; dj < 5; dj++) {
            int ccol = q + dj;
            #pragma unroll
            for (int a = 0; a < 8; a++) {
                int trow = (rb << 2) + a;
                float4 v = tile_s[(trow * 12 + ccol) * 17 + s];
                #pragma unroll
                for (int k = 0; k < 4; k++) {
                    if (k < a - 4 || k > a) continue;   // compile-time pruned
                    int nl = (((rb << 2) + k) << 3) + q;
                    float w = wts[nl][(a - k) * 5 + dj];
                    acc[sl][k].x += w * v.x;
                    acc[sl][k].y += w * v.y;
                    acc[sl][k].z += w * v.z;
                    acc[sl][k].w += w * v.w;
                }
            }
        }
    }

    #pragma unroll
    for (int k = 0; k < 4; k++) {
        float ss = acc[0][k].x * acc[0][k].x + acc[0][k].y * acc[0][k].y +
                   acc[0][k].z * acc[0][k].z + acc[0][k].w * acc[0][k].w +
                   acc[1][k].x * acc[1][k].x + acc[1][k].y * acc[1][k].y +
                   acc[1][k].z * acc[1][k].z + acc[1][k].w * acc[1][k].w;
        ss += __shfl_xor(ss, 1, 64);
        ss += __shfl_xor(ss, 2, 64);
        ss += __shfl_xor(ss, 4, 64);
        ss += __shfl_xor(ss, 8, 64);
        float rs = 1.0f / (sqrtf(ss) + EPSF);
        int gp = (ti0 + (rb << 2) + k) * WW + (tj0 + q);
        float* orow = hout + (((size_t)(b << 14) + gp) << 7);
        float4 r0 = {acc[0][k].x * rs, acc[0][k].y * rs, acc[0][k].z * rs, acc[0][k].w * rs};
        float4 r1 = {acc[1][k].x * rs, acc[1][k].y * rs, acc[1][k].z * rs, acc[1][k].w * rs};
        *(float4*)(orow + (s << 2)) = r0;
        *(float4*)(orow + 64 + (s << 2)) = r1;
    }
}

// ---------------- final iteration + fused mask head ----------------------
// Same compute as prop_kernel, but the final h never touches global:
// logits = h @ w_mask computed in-register, reduced across the 16
// channel-slot lanes via shfl_xor(4,8) into 4 LDS slots (overlaid on the
// freed tile_s region; wm staged there too with x17 pad to kill the
// stride-16 bank conflict), then the proven 4-slot softmax phase.
__global__ __launch_bounds__(256) void prop_last_kernel(
    const float* __restrict__ hin, const float* __restrict__ wT,
    const float* __restrict__ wm, float* __restrict__ out)
{
    __shared__ float4 tile_s[144 * 17];
    __shared__ float wts[64][36];
    const int t = threadIdx.x;
    const int x = blockIdx.x & 7;
    const int r = blockIdx.x >> 3;
    const int g_tr = (x << 2) + (r >> 4);
    const int b   = g_tr >> 4;
    const int ti0 = (g_tr & 15) << 3;
    const int tj0 = (r & 15) << 3;

    {
        const float* wbase = wT + (((size_t)(b << 14) + ti0 * WW + tj0) << 5);
        for (int idx = t; idx < 512; idx += 256) {
            int p = idx >> 6, rest = idx & 63;
            float4 v = *(const float4*)(wbase + (((size_t)p * WW) << 5) + (rest << 2));
            int nl = (p << 3) + (rest >> 3);
            int c4 = (rest & 7) << 2;
            *(float4*)&wts[nl][c4] = v;
        }
    }

    const int s  = t & 15;
    const int g  = t >> 4;
    const int q  = g & 7;
    const int rb = g >> 3;

    const float* hb = hin + ((size_t)b << 21);

    float4 acc[2][4];
    #pragma unroll
    for (int sl = 0; sl < 2; sl++)
        #pragma unroll
        for (int k = 0; k < 4; k++) acc[sl][k] = {0.f, 0.f, 0.f, 0.f};

    #pragma unroll
    for (int sl = 0; sl < 2; sl++) {
        if (sl) __syncthreads();
        int c0 = sl << 6;
        #pragma unroll
        for (int a0 = 0; a0 < 144; a0 += 16) {
            int a = a0 + g;
            int ar = a / 12, ac = a - ar * 12;
            int gi = min(max(ti0 + ar - 2, 0), HH - 1);
            int gj = min(max(tj0 + ac - 2, 0), WW - 1);
            tile_s[a * 17 + s] =
                *(const float4*)(hb + ((size_t)(gi * WW + gj) << 7) + c0 + (s << 2));
        }
        __syncthreads();

        #pragma unroll
        for (int dj = 0; dj < 5; dj++) {
            int ccol = q + dj;
            #pragma unroll
            for (int a = 0; a < 8; a++) {
                int trow = (rb << 2) + a;
                float4 v = tile_s[(trow * 12 + ccol) * 17 + s];
                #pragma unroll
                for (int k = 0; k < 4; k++) {
                    if (k < a - 4 || k > a) continue;
                    int nl = (((rb << 2) + k) << 3) + q;
                    float w = wts[nl][(a - k) * 5 + dj];
                    acc[sl][k].x += w * v.x;
                    acc[sl][k].y += w * v.y;
                    acc[sl][k].z += w * v.z;
                    acc[sl][k].w += w * v.w;
                }
            }
        }
    }

    // ---- LDS overlay: wm (padded x17) + partial-logit slots in tile_s ----
    __syncthreads();                       // all tile_s/wts reads done
    float* ldsf  = (float*)tile_s;
    float* wml   = ldsf;                   // 128 x 17 = 2176 floats
    float* partf = ldsf + 2304;            // 64 px x 4 slots x 20
    for (int idx = t; idx < QQ * MM; idx += 256) {
        int c = idx >> 4, m = idx & 15;
        wml[c * 17 + m] = wm[idx];
    }
    __syncthreads();

    #pragma unroll
    for (int k = 0; k < 4; k++) {
        float ss = acc[0][k].x * acc[0][k].x + acc[0][k].y * acc[0][k].y +
                   acc[0][k].z * acc[0][k].z + acc[0][k].w * acc[0][k].w +
                   acc[1][k].x * acc[1][k].x + acc[1][k].y * acc[1][k].y +
                   acc[1][k].z * acc[1][k].z + acc[1][k].w * acc[1][k].w;
        ss += __shfl_xor(ss, 1, 64);
        ss += __shfl_xor(ss, 2, 64);
        ss += __shfl_xor(ss, 4, 64);
        ss += __shfl_xor(ss, 8, 64);
        float rs = 1.0f / (sqrtf(ss) + EPSF);
        float h0[4] = {acc[0][k].x * rs, acc[0][k].y * rs, acc[0][k].z * rs, acc[0][k].w * rs};
        float h1[4] = {acc[1][k].x * rs, acc[1][k].y * rs, acc[1][k].z * rs, acc[1][k].w * rs};

        float4 lg0 = {0,0,0,0}, lg1 = lg0, lg2 = lg0, lg3 = lg0;
        #pragma unroll
        for (int j = 0; j < 4; j++) {
            {   // c = 4s + j
                const float* row = wml + (((s << 2) + j) * 17);
                float v = h0[j];
                lg0.x += v * row[0];  lg0.y += v * row[1];
                lg0.z += v * row[2];  lg0.w += v * row[3];
                lg1.x += v * row[4];  lg1.y += v * row[5];
                lg1.z += v * row[6];  lg1.w += v * row[7];
                lg2.x += v * row[8];  lg2.y += v * row[9];
                lg2.z += v * row[10]; lg2.w += v * row[11];
                lg3.x += v * row[12]; lg3.y += v * row[13];
                lg3.z += v * row[14]; lg3.w += v * row[15];
            }
            {   // c = 64 + 4s + j
                const float* row = wml + ((64 + (s << 2) + j) * 17);
                float v = h1[j];
                lg0.x += v * row[0];  lg0.y += v * row[1];
                lg0.z += v * row[2];  lg0.w += v * row[3];
                lg1.x += v * row[4];  lg1.y += v * row[5];
                lg1.z += v * row[6];  lg1.w += v * row[7];
                lg2.x += v * row[8];  lg2.y += v * row[9];
                lg2.z += v * row[10]; lg2.w += v * row[11];
                lg3.x += v * row[12]; lg3.y += v * row[13];
                lg3.z += v * row[14]; lg3.w += v * row[15];
            }
        }
        // reduce the 16 channel-slot lanes into 4 LDS slots (classes s&3)
        #define RED4(V) \
            V.x += __shfl_xor(V.x, 4, 64); V.y += __shfl_xor(V.y, 4, 64); \
            V.z += __shfl_xor(V.z, 4, 64); V.w += __shfl_xor(V.w, 4, 64); \
            V.x += __shfl_xor(V.x, 8, 64); V.y += __shfl_xor(V.y, 8, 64); \
            V.z += __shfl_xor(V.z, 8, 64); V.w += __shfl_xor(V.w, 8, 64);
        RED4(lg0) RED4(lg1) RED4(lg2) RED4(lg3)
        #undef RED4
        if (s < 4) {
            int p = (((rb << 2) + k) << 3) + q;   // px 0..63
            float* pr = partf + (size_t)((p << 2) + s) * 20;
            *(float4*)(pr + 0)  = lg0;
            *(float4*)(pr + 4)  = lg1;
            *(float4*)(pr + 8)  = lg2;
            *(float4*)(pr + 12) = lg3;
        }
    }
    __syncthreads();

    // ---- phase 2: 4-slot reduce + softmax(16) + transposed write --------
    {
        const int px2 = t >> 2, s2 = t & 3;
        float4 rr = {0, 0, 0, 0};
        #pragma unroll
        for (int ss2 = 0; ss2 < 4; ss2++) {
            float4 v = *(const float4*)(partf + (size_t)((px2 << 2) + ss2) * 20 + (s2 << 2));
            rr.x += v.x; rr.y += v.y; rr.z += v.z; rr.w += v.w;
        }
        float mx = fmaxf(fmaxf(rr.x, rr.y), fmaxf(rr.z, rr.w));
        mx = fmaxf(mx, __shfl_xor(mx, 1, 64));
        mx = fmaxf(mx, __shfl_xor(mx, 2, 64));
        float4 e = {expf(rr.x - mx), expf(rr.y - mx), expf(rr.z - mx), expf(rr.w - mx)};
        float ls = e.x + e.y + e.z + e.w;
        ls += __shfl_xor(ls, 1, 64);
        ls += __shfl_xor(ls, 2, 64);
        float inv = 1.0f / ls;
        int gp2 = (ti0 + (px2 >> 3)) * WW + tj0 + (px2 & 7);
        float* ob = out + (((size_t)((b << 4) + (s2 << 2))) << 14) + gp2;
        ob[0]             = e.x * inv;
        ob[1 << 14]       = e.y * inv;
        ob[2 << 14]       = e.z * inv;
        ob[3 * (1 << 14)] = e.w * inv;
    }
}

extern "C" void kernel_launch(void* const* d_in, const int* in_sizes, int n_in,
                              void* d_out, int out_size, void* d_ws, size_t ws_size,
                              hipStream_t stream)
{
    const float* x     = (const float*)d_in[0];
    // d_in[1] = edges (int32) -- unused: row/col are analytic
    const float* w1    = (const float*)d_in[2];
    const float* b1    = (const float*)d_in[3];
    const float* w2    = (const float*)d_in[4];
    const float* b2    = (const float*)d_in[5];
    const float* wk    = (const float*)d_in[6];
    const float* bk    = (const float*)d_in[7];
    const float* wq    = (const float*)d_in[8];
    const float* hinit = (const float*)d_in[9];
    const float* wm    = (const float*)d_in[10];
    float* out = (float*)d_out;

    char* ws = (char*)d_ws;
    size_t off = 0;
    auto alloc = [&](size_t bytes) -> void* {
        void* p = ws + off;
        off += (bytes + 255) & ~(size_t)255;
        return p;
    };
    float* feat1 = (float*)alloc((size_t)NBATCH * NPIX * DD * 4);
    float* feat2 = (float*)alloc((size_t)NBATCH * NPIX * DD * 4);
    float* ksb   = (float*)alloc((size_t)NBATCH * NPIX * DD * 4);
    float* qsb   = (float*)alloc((size_t)NBATCH * NPIX * DD * 4);
    float* knorm = (float*)alloc((size_t)NBATCH * NPIX * 4);
    float* qnorm = (float*)alloc((size_t)NBATCH * NPIX * 4);
    float* wT    = (float*)alloc((size_t)NBATCH * NPIX * 32 * 4);
    float* hA    = (float*)alloc((size_t)NBATCH * NPIX * QQ * 4);
    float* hB    = (float*)alloc((size_t)NBATCH * NPIX * QQ * 4);

    conv1_kernel<<<512, 256, 0, stream>>>(x, w1, b1, feat1);
    conv2_kernel<<<512, 256, 0, stream>>>(feat1, w2, b2, feat2);
    kq_kernel<<<4096, 256, 0, stream>>>(feat2, wk, bk, wq, ksb, qsb, knorm, qnorm);
    edge_kernel<<<512, 256, 0, stream>>>(ksb, qsb, knorm, qnorm, wT);

    // 31 propagation dispatches + final dispatch fused with the mask head
    const float* src = hinit;
    float* dst = hA;
    for (int it = 0; it < 31; it++) {
        prop_kernel<<<512, 256, 0, stream>>>(src, dst, wT);
        src = dst;
        dst = (dst == hA) ? hB : hA;
    }
    prop_last_kernel<<<512, 256, 0, stream>>>(src, wT, wm, out);
}

// Round 7
// 437.576 us; speedup vs baseline: 1.9907x; 1.1635x over previous
//
#include <hip/hip_runtime.h>
#include <hip/hip_fp16.h>
#include <math.h>

#define HH 128
#define WW 128
#define NPIX 16384
#define CIN 3
#define DD 32
#define QQ 128
#define MM 16
#define NBATCH 2
#define EPSF 1e-8f

// ---------------- conv1: 3x3, 3->32, relu, zero-pad SAME ----------------
__global__ __launch_bounds__(256) void conv1_kernel(
    const float* __restrict__ x, const float* __restrict__ w1,
    const float* __restrict__ b1, float* __restrict__ out)
{
    __shared__ float wlds[9 * CIN * DD];
    int t = threadIdx.x;
    for (int idx = t; idx < 9 * CIN * DD / 4; idx += 256)
        ((float4*)wlds)[idx] = ((const float4*)w1)[idx];
    __syncthreads();

    int ocq = t & 3;
    int pl  = t >> 2;
    int blk = blockIdx.x;                   // 512
    int b   = blk >> 8;
    int pix = (blk & 255) * 64 + pl;
    int i = pix >> 7, j = pix & 127;
    int ocb = ocq << 3;

    float4 acc0 = *(const float4*)(b1 + ocb);
    float4 acc1 = *(const float4*)(b1 + ocb + 4);
    #pragma unroll
    for (int dy = 0; dy < 3; dy++) {
        int ii = i + dy - 1;
        if (ii < 0 || ii >= HH) continue;
        #pragma unroll
        for (int dx = 0; dx < 3; dx++) {
            int jj = j + dx - 1;
            if (jj < 0 || jj >= WW) continue;
            const float* fr = x + ((size_t)((b << 14) + ii * WW + jj)) * CIN;
            float in0 = fr[0], in1 = fr[1], in2 = fr[2];
            const float* wp = wlds + (size_t)((dy * 3 + dx) * CIN) * DD + ocb;
            #pragma unroll
            for (int ic = 0; ic < 3; ic++) {
                float inv = (ic == 0) ? in0 : (ic == 1) ? in1 : in2;
                float4 w0 = *(const float4*)(wp + ic * DD);
                float4 w1v = *(const float4*)(wp + ic * DD + 4);
                acc0.x += inv * w0.x;  acc0.y += inv * w0.y;
                acc0.z += inv * w0.z;  acc0.w += inv * w0.w;
                acc1.x += inv * w1v.x; acc1.y += inv * w1v.y;
                acc1.z += inv * w1v.z; acc1.w += inv * w1v.w;
            }
        }
    }
    float* op = out + (((size_t)(b << 14) + pix) << 5) + ocb;
    float4 r0 = {fmaxf(acc0.x, 0.f), fmaxf(acc0.y, 0.f), fmaxf(acc0.z, 0.f), fmaxf(acc0.w, 0.f)};
    float4 r1 = {fmaxf(acc1.x, 0.f), fmaxf(acc1.y, 0.f), fmaxf(acc1.z, 0.f), fmaxf(acc1.w, 0.f)};
    *(float4*)op = r0;
    *(float4*)(op + 4) = r1;
}

// ---------------- conv2: 3x3, 32->32, relu ----------------
__global__ __launch_bounds__(256) void conv2_kernel(
    const float* __restrict__ fin, const float* __restrict__ w2,
    const float* __restrict__ b2, float* __restrict__ out)
{
    __shared__ float wlds[9 * DD * DD];    // 36.9 KB
    int t = threadIdx.x;
    for (int idx = t; idx < 9 * DD * DD / 4; idx += 256)
        ((float4*)wlds)[idx] = ((const float4*)w2)[idx];
    __syncthreads();

    int ocq = t & 3;
    int pl  = t >> 2;
    int blk = blockIdx.x;                   // 512
    int b   = blk >> 8;
    int pix = (blk & 255) * 64 + pl;
    int i = pix >> 7, j = pix & 127;
    int ocb = ocq << 3;

    float4 acc0 = *(const float4*)(b2 + ocb);
    float4 acc1 = *(const float4*)(b2 + ocb + 4);
    #pragma unroll
    for (int dy = 0; dy < 3; dy++) {
        int ii = i + dy - 1;
        if (ii < 0 || ii >= HH) continue;
        #pragma unroll
        for (int dx = 0; dx < 3; dx++) {
            int jj = j + dx - 1;
            if (jj < 0 || jj >= WW) continue;
            const float* fr = fin + (((size_t)(b << 14) + ii * WW + jj)) * DD;
            float iv[DD];
            #pragma unroll
            for (int c = 0; c < DD / 4; c++)
                ((float4*)iv)[c] = *(const float4*)(fr + c * 4);
            const float* wp = wlds + (size_t)((dy * 3 + dx) * DD) * DD + ocb;
            #pragma unroll
            for (int ic = 0; ic < DD; ic++) {
                float inv = iv[ic];
                float4 w0 = *(const float4*)(wp + ic * DD);
                float4 w1v = *(const float4*)(wp + ic * DD + 4);
                acc0.x += inv * w0.x;  acc0.y += inv * w0.y;
                acc0.z += inv * w0.z;  acc0.w += inv * w0.w;
                acc1.x += inv * w1v.x; acc1.y += inv * w1v.y;
                acc1.z += inv * w1v.z; acc1.w += inv * w1v.w;
            }
        }
    }
    float* op = out + (((size_t)(b << 14) + pix) << 5) + ocb;
    float4 r0 = {fmaxf(acc0.x, 0.f), fmaxf(acc0.y, 0.f), fmaxf(acc0.z, 0.f), fmaxf(acc0.w, 0.f)};
    float4 r1 = {fmaxf(acc1.x, 0.f), fmaxf(acc1.y, 0.f), fmaxf(acc1.z, 0.f), fmaxf(acc1.w, 0.f)};
    *(float4*)op = r0;
    *(float4*)(op + 4) = r1;
}

// ---------------- k/q 1x1 projections + row norms ----------------
__global__ __launch_bounds__(256) void kq_kernel(
    const float* __restrict__ fin, const float* __restrict__ wk,
    const float* __restrict__ bk, const float* __restrict__ wq,
    float* __restrict__ ksb, float* __restrict__ qsb,
    float* __restrict__ knorm, float* __restrict__ qnorm)
{
    int g  = blockIdx.x * 256 + threadIdx.x;  // B*N*32
    int oc = g & 31;
    int bp = g >> 5;
    const float* fr = fin + (size_t)bp * DD;
    float ak = bk[oc], aq = 0.0f;
    #pragma unroll
    for (int ic = 0; ic < DD; ic += 4) {
        float4 fv = *(const float4*)(fr + ic);
        ak += fv.x * wk[(ic + 0) * DD + oc];
        ak += fv.y * wk[(ic + 1) * DD + oc];
        ak += fv.z * wk[(ic + 2) * DD + oc];
        ak += fv.w * wk[(ic + 3) * DD + oc];
        aq += fv.x * wq[(ic + 0) * DD + oc];
        aq += fv.y * wq[(ic + 1) * DD + oc];
        aq += fv.z * wq[(ic + 2) * DD + oc];
        aq += fv.w * wq[(ic + 3) * DD + oc];
    }
    ksb[g] = ak;
    qsb[g] = aq;
    float ssk = ak * ak, ssq = aq * aq;
    #pragma unroll
    for (int m = 1; m < 32; m <<= 1) {
        ssk += __shfl_xor(ssk, m, 64);
        ssq += __shfl_xor(ssq, m, 64);
    }
    if (oc == 0) {
        knorm[bp] = sqrtf(ssk);
        qnorm[bp] = sqrtf(ssq);
    }
}

// ---------------- edge scores: exp(cosine), UNSCALED ---------------------
// Global softmax denominator cancels under per-iteration normalization
// (proven R5/R6: absmax unchanged). wT stores raw e^cos in [0.37, 2.72].
__global__ __launch_bounds__(256) void edge_kernel(
    const float* __restrict__ ksb, const float* __restrict__ qsb,
    const float* __restrict__ knorm, const float* __restrict__ qnorm,
    float* __restrict__ wT)
{
    __shared__ float kt[144][36];   // +4 pad: breaks 32-stride bank aliasing
    __shared__ float qt[64][36];
    __shared__ float kn[144];
    __shared__ float qn[64];
    const int t   = threadIdx.x;
    const int blk = blockIdx.x;     // 512
    const int b   = blk >> 8;
    const int tl  = blk & 255;
    const int ti0 = (tl >> 4) << 3, tj0 = (tl & 15) << 3;
    const float* kb = ksb + ((size_t)b << 19);
    const float* qb = qsb + ((size_t)b << 19);

    for (int idx = t; idx < 144 * 8; idx += 256) {
        int row = idx >> 3, quad = idx & 7;
        int ar = row / 12, ac = row - ar * 12;
        int gi = min(max(ti0 + ar - 2, 0), HH - 1);
        int gj = min(max(tj0 + ac - 2, 0), WW - 1);
        *(float4*)&kt[row][quad << 2] =
            *(const float4*)(kb + ((size_t)(gi * WW + gj) << 5) + (quad << 2));
    }
    for (int idx = t; idx < 64 * 8; idx += 256) {
        int row = idx >> 3, quad = idx & 7;
        int gp = (ti0 + (row >> 3)) * WW + tj0 + (row & 7);
        *(float4*)&qt[row][quad << 2] =
            *(const float4*)(qb + ((size_t)gp << 5) + (quad << 2));
    }
    if (t < 144) {
        int ar = t / 12, ac = t - ar * 12;
        int gi = min(max(ti0 + ar - 2, 0), HH - 1);
        int gj = min(max(tj0 + ac - 2, 0), WW - 1);
        kn[t] = knorm[(b << 14) + gi * WW + gj];
    } else if (t < 208) {
        int r2 = t - 144;
        int gp = (ti0 + (r2 >> 3)) * WW + tj0 + (r2 & 7);
        qn[r2] = qnorm[(b << 14) + gp];
    }
    __syncthreads();

    const int nl = t >> 2, s = t & 3;
    const int p = nl >> 3, q = nl & 7;
    float4 qv[8];
    #pragma unroll
    for (int c = 0; c < 8; c++) qv[c] = *(const float4*)&qt[nl][c << 2];
    const float qnv = qn[nl];
    const int gp = (ti0 + p) * WW + tj0 + q;
    float* wrow = wT + (((size_t)(b << 14) + gp) << 5);
    for (int o = s; o < 25; o += 4) {
        int di = o / 5, dj = o - di * 5;      // 0..4
        int krow = (p + di) * 12 + (q + dj);  // halo coords
        const float* kr = &kt[krow][0];
        float dot = 0.0f;
        #pragma unroll
        for (int c = 0; c < 8; c++) {
            float4 kv = *(const float4*)(kr + (c << 2));
            dot += qv[c].x * kv.x + qv[c].y * kv.y + qv[c].z * kv.z + qv[c].w * kv.w;
        }
        float den = fmaxf(qnv * kn[krow], EPSF);
        wrow[o] = expf(dot / den);
    }
}

// ---------------- hinit fp32 -> fp16 ------------------------------------
__global__ __launch_bounds__(256) void h2half_kernel(
    const float* __restrict__ hin, __half* __restrict__ hout)
{
    int i = blockIdx.x * 256 + threadIdx.x;   // 524288 uint4 tasks
    const float4* s = (const float4*)hin + (size_t)i * 2;
    float4 a = s[0], c = s[1];
    __half2 p0 = __floats2half2_rn(a.x, a.y);
    __half2 p1 = __floats2half2_rn(a.z, a.w);
    __half2 p2 = __floats2half2_rn(c.x, c.y);
    __half2 p3 = __floats2half2_rn(c.z, c.w);
    uint4 o;
    o.x = *(unsigned int*)&p0;
    o.y = *(unsigned int*)&p1;
    o.z = *(unsigned int*)&p2;
    o.w = *(unsigned int*)&p3;
    ((uint4*)hout)[i] = o;
}

// ---------------- one propagation iteration ------------------------------
// PROVEN R0 compute structure (fp32 LDS tile, 2 channel slabs, identical
// inner loop). Only the GLOBAL h storage is fp16: per-XCD working set
// drops 4.7 MB -> 2.6 MB (< 4 MB L2/XCD), breaking the LRU thrash that
// R6 counters exposed (FETCH 17.8 MB/iter = full h L2 miss). fp16<->fp32
// conversion happens ONLY in the 9-iter staging loop and epilogue (~100
// ops/thread) -- NOT inside the unrolled compute loop (R5's mistake).
__global__ __launch_bounds__(256) void prop_kernel(
    const __half* __restrict__ hin, __half* __restrict__ hout,
    const float* __restrict__ wT)
{
    __shared__ float4 tile_s[144 * 17];    // 12x12 px x 16 slots fp32, pad 17
    __shared__ float wts[64][36];          // raw e^cos weights
    const int t = threadIdx.x;
    const int x = blockIdx.x & 7;          // XCD slab
    const int r = blockIdx.x >> 3;         // 0..63 within slab
    const int g_tr = (x << 2) + (r >> 4);  // global tile-row 0..31
    const int b   = g_tr >> 4;
    const int ti0 = (g_tr & 15) << 3;
    const int tj0 = (r & 15) << 3;

    {
        const float* wbase = wT + (((size_t)(b << 14) + ti0 * WW + tj0) << 5);
        for (int idx = t; idx < 512; idx += 256) {
            int p = idx >> 6, rest = idx & 63;
            float4 v = *(const float4*)(wbase + (((size_t)p * WW) << 5) + (rest << 2));
            int nl = (p << 3) + (rest >> 3);
            int c4 = (rest & 7) << 2;
            *(float4*)&wts[nl][c4] = v;
        }
    }

    const int s  = t & 15;
    const int g  = t >> 4;
    const int q  = g & 7;
    const int rb = g >> 3;

    const __half* hb = hin + ((size_t)b << 21);   // b * 16384 * 128 halves

    float4 acc[2][4];
    #pragma unroll
    for (int sl = 0; sl < 2; sl++)
        #pragma unroll
        for (int k = 0; k < 4; k++) acc[sl][k] = {0.f, 0.f, 0.f, 0.f};

    #pragma unroll
    for (int sl = 0; sl < 2; sl++) {
        if (sl) __syncthreads();           // WAR: slab0 reads done
        int c0 = sl << 6;
        #pragma unroll
        for (int a0 = 0; a0 < 144; a0 += 16) {
            int a = a0 + g;
            int ar = a / 12, ac = a - ar * 12;
            int gi = min(max(ti0 + ar - 2, 0), HH - 1);
            int gj = min(max(tj0 + ac - 2, 0), WW - 1);
            // fp16 global read (8B/lane, coalesced) -> fp32 LDS
            uint2 u = *(const uint2*)(hb + ((size_t)(gi * WW + gj) << 7) + c0 + (s << 2));
            __half2 h0 = *(__half2*)&u.x;
            __half2 h1 = *(__half2*)&u.y;
            float2 f0 = __half22float2(h0);
            float2 f1 = __half22float2(h1);
            tile_s[a * 17 + s] = {f0.x, f0.y, f1.x, f1.y};
        }
        __syncthreads();

        #pragma unroll
        for (int dj = 0; dj < 5; dj++) {
            int ccol = q + dj;
            #pragma unroll
            for (int a = 0; a < 8; a++) {
                int trow = (rb << 2) + a;
                float4 v = tile_s[(trow * 12 + ccol) * 17 + s];
                #pragma unroll
                for (int k = 0; k < 4; k++) {
                    if (k < a - 4 || k > a) continue;   // compile-time pruned
                    int nl = (((rb << 2) + k) << 3) + q;
                    float w = wts[nl][(a - k) * 5 + dj];
                    acc[sl][k].x += w * v.x;
                    acc[sl][k].y += w * v.y;
                    acc[sl][k].z += w * v.z;
                    acc[sl][k].w += w * v.w;
                }
            }
        }
    }

    #pragma unroll
    for (int k = 0; k < 4; k++) {
        float ss = acc[0][k].x * acc[0][k].x + acc[0][k].y * acc[0][k].y +
                   acc[0][k].z * acc[0][k].z + acc[0][k].w * acc[0][k].w +
                   acc[1][k].x * acc[1][k].x + acc[1][k].y * acc[1][k].y +
                   acc[1][k].z * acc[1][k].z + acc[1][k].w * acc[1][k].w;
        ss += __shfl_xor(ss, 1, 64);
        ss += __shfl_xor(ss, 2, 64);
        ss += __shfl_xor(ss, 4, 64);
        ss += __shfl_xor(ss, 8, 64);
        float rs = 1.0f / (sqrtf(ss) + EPSF);
        int gp = (ti0 + (rb << 2) + k) * WW + (tj0 + q);
        __half* orow = hout + (((size_t)(b << 14) + gp) << 7);
        __half2 p0 = __floats2half2_rn(acc[0][k].x * rs, acc[0][k].y * rs);
        __half2 p1 = __floats2half2_rn(acc[0][k].z * rs, acc[0][k].w * rs);
        __half2 p2 = __floats2half2_rn(acc[1][k].x * rs, acc[1][k].y * rs);
        __half2 p3 = __floats2half2_rn(acc[1][k].z * rs, acc[1][k].w * rs);
        uint2 o0, o1;
        o0.x = *(unsigned int*)&p0;  o0.y = *(unsigned int*)&p1;
        o1.x = *(unsigned int*)&p2;  o1.y = *(unsigned int*)&p3;
        *(uint2*)(orow + (s << 2))      = o0;
        *(uint2*)(orow + 64 + (s << 2)) = o1;
    }
}

// ---------------- mask head: h(fp16) @ w_mask, softmax(16), transpose ----
__global__ __launch_bounds__(256) void mask_kernel(
    const __half* __restrict__ h, const float* __restrict__ wm,
    float* __restrict__ out)
{
    __shared__ float wls[QQ * MM];      // 8 KB, [c][m] native layout
    __shared__ float part[64][4][20];   // [px][slot][16m + pad]
    const int t = threadIdx.x;
    for (int idx = t; idx < QQ * MM / 4; idx += 256)
        ((float4*)wls)[idx] = ((const float4*)wm)[idx];
    const int blk = blockIdx.x;         // 512
    const int b   = blk >> 8;
    const int n0  = (blk & 255) << 6;
    const int px  = t >> 2, s = t & 3;
    const __half* hr = h + (((size_t)(b << 14) + n0 + px) << 7);

    float hv[32];
    #pragma unroll
    for (int k = 0; k < 32; k++) hv[k] = __half2float(hr[s + (k << 2)]);
    __syncthreads();

    float4 a0 = {0,0,0,0}, a1 = a0, a2 = a0, a3 = a0;
    #pragma unroll
    for (int k = 0; k < 32; k++) {
        const float4* wrow = (const float4*)(wls + ((s + (k << 2)) << 4));
        float v = hv[k];
        float4 w0 = wrow[0], w1 = wrow[1], w2 = wrow[2], w3 = wrow[3];
        a0.x += v * w0.x; a0.y += v * w0.y; a0.z += v * w0.z; a0.w += v * w0.w;
        a1.x += v * w1.x; a1.y += v * w1.y; a1.z += v * w1.z; a1.w += v * w1.w;
        a2.x += v * w2.x; a2.y += v * w2.y; a2.z += v * w2.z; a2.w += v * w2.w;
        a3.x += v * w3.x; a3.y += v * w3.y; a3.z += v * w3.z; a3.w += v * w3.w;
    }
    *(float4*)&part[px][s][0]  = a0;
    *(float4*)&part[px][s][4]  = a1;
    *(float4*)&part[px][s][8]  = a2;
    *(float4*)&part[px][s][12] = a3;
    __syncthreads();

    float4 rr = {0,0,0,0};
    #pragma unroll
    for (int ss = 0; ss < 4; ss++) {
        float4 v = *(const float4*)&part[px][ss][s << 2];
        rr.x += v.x; rr.y += v.y; rr.z += v.z; rr.w += v.w;
    }
    float mx = fmaxf(fmaxf(rr.x, rr.y), fmaxf(rr.z, rr.w));
    mx = fmaxf(mx, __shfl_xor(mx, 1, 64));
    mx = fmaxf(mx, __shfl_xor(mx, 2, 64));
    float4 e = {expf(rr.x - mx), expf(rr.y - mx), expf(rr.z - mx), expf(rr.w - mx)};
    float ls = e.x + e.y + e.z + e.w;
    ls += __shfl_xor(ls, 1, 64);
    ls += __shfl_xor(ls, 2, 64);
    float inv = 1.0f / ls;
    float* ob = out + (((size_t)((b << 4) + (s << 2))) << 14) + n0 + px;
    ob[0]             = e.x * inv;
    ob[1 << 14]       = e.y * inv;
    ob[2 << 14]       = e.z * inv;
    ob[3 * (1 << 14)] = e.w * inv;
}

extern "C" void kernel_launch(void* const* d_in, const int* in_sizes, int n_in,
                              void* d_out, int out_size, void* d_ws, size_t ws_size,
                              hipStream_t stream)
{
    const float* x     = (const float*)d_in[0];
    // d_in[1] = edges (int32) -- unused: row/col are analytic
    const float* w1    = (const float*)d_in[2];
    const float* b1    = (const float*)d_in[3];
    const float* w2    = (const float*)d_in[4];
    const float* b2    = (const float*)d_in[5];
    const float* wk    = (const float*)d_in[6];
    const float* bk    = (const float*)d_in[7];
    const float* wq    = (const float*)d_in[8];
    const float* hinit = (const float*)d_in[9];
    const float* wm    = (const float*)d_in[10];
    float* out = (float*)d_out;

    char* ws = (char*)d_ws;
    size_t off = 0;
    auto alloc = [&](size_t bytes) -> void* {
        void* p = ws + off;
        off += (bytes + 255) & ~(size_t)255;
        return p;
    };
    float* feat1 = (float*)alloc((size_t)NBATCH * NPIX * DD * 4);
    float* feat2 = (float*)alloc((size_t)NBATCH * NPIX * DD * 4);
    float* ksb   = (float*)alloc((size_t)NBATCH * NPIX * DD * 4);
    float* qsb   = (float*)alloc((size_t)NBATCH * NPIX * DD * 4);
    float* knorm = (float*)alloc((size_t)NBATCH * NPIX * 4);
    float* qnorm = (float*)alloc((size_t)NBATCH * NPIX * 4);
    float* wT    = (float*)alloc((size_t)NBATCH * NPIX * 32 * 4);
    __half* h16A = (__half*)alloc((size_t)NBATCH * NPIX * QQ * 2);
    __half* h16B = (__half*)alloc((size_t)NBATCH * NPIX * QQ * 2);

    conv1_kernel<<<512, 256, 0, stream>>>(x, w1, b1, feat1);
    conv2_kernel<<<512, 256, 0, stream>>>(feat1, w2, b2, feat2);
    kq_kernel<<<4096, 256, 0, stream>>>(feat2, wk, bk, wq, ksb, qsb, knorm, qnorm);
    edge_kernel<<<512, 256, 0, stream>>>(ksb, qsb, knorm, qnorm, wT);

    h2half_kernel<<<2048, 256, 0, stream>>>(hinit, h16A);

    const __half* src = h16A;
    __half* dst = h16B;
    for (int it = 0; it < 32; it++) {
        prop_kernel<<<512, 256, 0, stream>>>(src, dst, wT);
        src = dst;
        dst = (dst == h16A) ? h16B : h16A;
    }
    mask_kernel<<<512, 256, 0, stream>>>(src, wm, out);
}